// Round 7
// baseline (140.107 us; speedup 1.0000x reference)
//
#include <hip/hip_runtime.h>
#include <math.h>

// Symmetry_Set_Basis, 3-kernel pure-phase split:
//   K1: per-wave partial power sums of v (p1..p4) and q (s1,s2) -> ws   [no barriers]
//   K2: per-row f64 epilogue (Newton identities, signed roots, 7x7 GEMV,
//       norms) -> A_b, D_b                                              [1 thread/row]
//   K3: out[b,n] = q[b,n]*A_b + D_b                                     [pure stream]
// R5 finding: fused kernel was phase-aligned at 1.6 TB/s (20% peak) while the
// harness fill hits 6.4 TB/s; epilogue cost was irrelevant (R2==R5 time).

constexpr int NTH = 256;   // threads per block
constexpr int NN  = 4096;  // set size (row length)

// ---------------- K1: reduce ----------------
// block b, wave w (0..3) reduces chunk [w*1024, (w+1)*1024) of row b.
// lane l handles float4s w*256 + l + {0,64,128,192}. Writes 6 f32 partials.
__global__ __launch_bounds__(NTH) void k1_reduce(
    const float* __restrict__ q,
    const float* __restrict__ v,
    float* __restrict__ part)   // [B][4][6] f32
{
    const int b = blockIdx.x;
    const int t = threadIdx.x;
    const int w = t >> 6, l = t & 63;
    const float4* q4 = (const float4*)(q + (size_t)b * NN) + (w << 8);
    const float4* v4 = (const float4*)(v + (size_t)b * NN) + (w << 8);

    float4 qv[4], vv[4];
    #pragma unroll
    for (int i = 0; i < 4; ++i) {
        qv[i] = q4[l + (i << 6)];
        vv[i] = v4[l + (i << 6)];
    }

    float p1 = 0.f, p2 = 0.f, p3 = 0.f, p4 = 0.f, s1 = 0.f, s2 = 0.f;
    #pragma unroll
    for (int i = 0; i < 4; ++i) {
        const float xs[4] = {vv[i].x, vv[i].y, vv[i].z, vv[i].w};
        const float qs[4] = {qv[i].x, qv[i].y, qv[i].z, qv[i].w};
        #pragma unroll
        for (int j = 0; j < 4; ++j) {
            const float x  = xs[j];
            const float x2 = x * x;
            p1 += x;  p2 += x2;  p3 += x2 * x;  p4 += x2 * x2;
            const float qq = qs[j];
            s1 += qq; s2 += qq * qq;
        }
    }

    float r[6] = {p1, p2, p3, p4, s1, s2};
    #pragma unroll
    for (int off = 32; off > 0; off >>= 1) {
        #pragma unroll
        for (int k = 0; k < 6; ++k) r[k] += __shfl_down(r[k], off, 64);
    }
    if (l == 0) {
        float* o = part + ((size_t)b * 4 + w) * 6;
        #pragma unroll
        for (int k = 0; k < 6; ++k) o[k] = r[k];
    }
}

// ---------------- K2: epilogue ----------------
__device__ inline double sroot2(double x) { return copysign(sqrt(fabs(x)), x); }
__device__ inline double sroot4(double x) { return copysign(sqrt(sqrt(fabs(x))), x); }
__device__ inline double sroot3(double x) {
    double a = fabs(x);
    if (a < 1e-300) return 0.0;
    double y = (double)exp2f(log2f((float)a) * (1.0f / 3.0f));
    y = (2.0 * y + a / (y * y)) * (1.0 / 3.0);
    y = (2.0 * y + a / (y * y)) * (1.0 / 3.0);
    return copysign(y, x);
}

__global__ __launch_bounds__(NTH) void k2_epilogue(
    const float* __restrict__ part,   // [B][4][6]
    const float* __restrict__ wq_w,   // [1,7]
    const float* __restrict__ wq_b,   // [7]
    const float* __restrict__ wk_w,   // [7,7] row-major
    const float* __restrict__ wk_b,   // [7]
    float2* __restrict__ AD,          // [B]
    int B)
{
    const int b = blockIdx.x * NTH + threadIdx.x;
    if (b >= B) return;
    const float* pp = part + (size_t)b * 24;

    double tot[6];
    #pragma unroll
    for (int k = 0; k < 6; ++k)
        tot[k] = (double)pp[k] + (double)pp[6 + k] +
                 (double)pp[12 + k] + (double)pp[18 + k];

    const double P1 = tot[0], P2 = tot[1], P3 = tot[2], P4 = tot[3];
    const double S1 = tot[4], S2 = tot[5];

    const double e1 = P1;
    const double e2 = (P1 * P1 - P2) * 0.5;
    const double e3 = (P1 * P1 * P1 - P3 - 3.0 * (P2 * P1 - P3)) / 6.0;
    const double e4 = (e3 * P1 - e2 * P2 + e1 * P3 - P4) * 0.25;

    double f[7];
    f[0] = e1;
    f[1] = sroot2(e2);
    f[2] = sroot3(e3);
    f[3] = sroot4(e4);
    f[4] = sroot2(P2);
    f[5] = sroot3(P3);
    f[6] = sroot4(P4);

    double ke[7];
    #pragma unroll
    for (int j = 0; j < 7; ++j) {
        double acc = (double)wk_b[j];
        #pragma unroll
        for (int i = 0; i < 7; ++i) acc += f[i] * (double)wk_w[i * 7 + j];
        ke[j] = acc;
    }

    const double sqrtN = sqrt((double)NN);
    double A = 0.0, D = 0.0;
    #pragma unroll
    for (int j = 0; j < 7; ++j) {
        const double wj  = (double)wq_w[j];
        const double bj  = (double)wq_b[j];
        const double knj = ke[j] / (sqrtN * fabs(ke[j]) + 1e-10);
        const double nq  = sqrt(wj * wj * S2 + 2.0 * wj * bj * S1 +
                                (double)NN * bj * bj) + 1e-10;
        const double g = knj * f[j] / nq;
        A += g * wj;
        D += g * bj;
    }
    AD[b] = make_float2((float)A, (float)D);
}

// ---------------- K3: apply ----------------
__global__ __launch_bounds__(NTH) void k3_apply(
    const float* __restrict__ q,
    const float2* __restrict__ AD,
    float* __restrict__ out)
{
    const int b = blockIdx.x;
    const int t = threadIdx.x;
    const float2 ad = AD[b];           // uniform addr -> s_load broadcast
    const float A = ad.x, D = ad.y;
    const float4* q4 = (const float4*)(q + (size_t)b * NN);
    float4*       o4 = (float4*)(out + (size_t)b * NN);
    #pragma unroll
    for (int i = 0; i < 4; ++i) {
        float4 x = q4[t + (i << 8)];
        float4 o;
        o.x = x.x * A + D;  o.y = x.y * A + D;
        o.z = x.z * A + D;  o.w = x.w * A + D;
        o4[t + (i << 8)] = o;
    }
}

extern "C" void kernel_launch(void* const* d_in, const int* in_sizes, int n_in,
                              void* d_out, int out_size, void* d_ws, size_t ws_size,
                              hipStream_t stream) {
    const float* q    = (const float*)d_in[0];
    // d_in[1] (k) is unused by the layer
    const float* v    = (const float*)d_in[2];
    const float* wq_w = (const float*)d_in[3];
    const float* wq_b = (const float*)d_in[4];
    const float* wk_w = (const float*)d_in[5];
    const float* wk_b = (const float*)d_in[6];
    float* out = (float*)d_out;

    const int B = in_sizes[0] / NN;  // 2048

    float*  part = (float*)d_ws;                         // B*24 f32 = 192 KB
    float2* AD   = (float2*)((char*)d_ws + (size_t)B * 24 * sizeof(float));

    k1_reduce  <<<B, NTH, 0, stream>>>(q, v, part);
    k2_epilogue<<<(B + NTH - 1) / NTH, NTH, 0, stream>>>(part, wq_w, wq_b,
                                                         wk_w, wk_b, AD, B);
    k3_apply   <<<B, NTH, 0, stream>>>(q, AD, out);
}